// Round 1
// baseline (37.552 us; speedup 1.0000x reference)
//
#include <hip/hip_runtime.h>

// ---------------------------------------------------------------------------
// Clifford algebra Cl(3,1,0) geometric product, DIM = 16 blades.
//   out[n][c] = sum_{i,j: i^j == c} sign(i,j) * a[n][i] * b[n][j]
// sign(i,j) = canonical-reordering parity * metric factor for contracted
// generators (e0,e1,e2 square to +1; e3 squares to -1).
// Table is built at compile time; after full unroll every sign folds into
// the FMA negate modifier -> 256 v_fma_f32 per row, zero table loads.
// ---------------------------------------------------------------------------

struct CayleyTab { signed char s[16][16]; };

constexpr CayleyTab build_tab() {
    CayleyTab t{};
    for (int i = 0; i < 16; ++i) {
        for (int j = 0; j < 16; ++j) {
            int sum = 0;
            // canonical reordering swap parity: sum_k popcount((i >> (k+1)) & j)
            for (int a = i >> 1; a; a >>= 1) {
                int m = a & j;
                while (m) { sum += (m & 1); m >>= 1; }
            }
            // metric: generator 3 (bit 3) squares to -1; bits 0..2 square to +1
            sum += ((i & j) >> 3) & 1;
            t.s[i][j] = (signed char)((sum & 1) ? -1 : 1);
        }
    }
    return t;
}

constexpr CayleyTab TAB = build_tab();

__device__ __forceinline__ float clip1000(float v) {
    return fminf(fmaxf(v, -1000.0f), 1000.0f);
}

__global__ __launch_bounds__(256) void clifford_gp_kernel(
        const float* __restrict__ a,
        const float* __restrict__ b,
        float* __restrict__ out,
        int nrows) {
    const int stride = gridDim.x * blockDim.x;
    for (int row = blockIdx.x * blockDim.x + threadIdx.x; row < nrows; row += stride) {
        const float4* a4 = reinterpret_cast<const float4*>(a) + (size_t)row * 4;
        const float4* b4 = reinterpret_cast<const float4*>(b) + (size_t)row * 4;

        float av[16], bv[16];
        #pragma unroll
        for (int k = 0; k < 4; ++k) {
            const float4 ta = a4[k];
            av[4 * k + 0] = ta.x; av[4 * k + 1] = ta.y;
            av[4 * k + 2] = ta.z; av[4 * k + 3] = ta.w;
            const float4 tb = b4[k];
            bv[4 * k + 0] = tb.x; bv[4 * k + 1] = tb.y;
            bv[4 * k + 2] = tb.z; bv[4 * k + 3] = tb.w;
        }

        float acc[16];
        #pragma unroll
        for (int c = 0; c < 16; ++c) acc[c] = 0.0f;

        #pragma unroll
        for (int i = 0; i < 16; ++i) {
            #pragma unroll
            for (int j = 0; j < 16; ++j) {
                const int c = i ^ j;
                if (TAB.s[i][j] > 0) acc[c] = fmaf(av[i],  bv[j], acc[c]);
                else                 acc[c] = fmaf(av[i], -bv[j], acc[c]);
            }
        }

        float4* o4 = reinterpret_cast<float4*>(out) + (size_t)row * 4;
        #pragma unroll
        for (int k = 0; k < 4; ++k) {
            float4 t;
            t.x = clip1000(acc[4 * k + 0]);
            t.y = clip1000(acc[4 * k + 1]);
            t.z = clip1000(acc[4 * k + 2]);
            t.w = clip1000(acc[4 * k + 3]);
            o4[k] = t;
        }
    }
}

extern "C" void kernel_launch(void* const* d_in, const int* in_sizes, int n_in,
                              void* d_out, int out_size, void* d_ws, size_t ws_size,
                              hipStream_t stream) {
    const float* a = (const float*)d_in[0];
    const float* b = (const float*)d_in[1];
    float* out = (float*)d_out;

    const int nrows = in_sizes[0] / 16;   // N = 1048576
    const int block = 256;
    int blocks = (nrows + block - 1) / block;
    if (blocks > 2048) blocks = 2048;     // grid-stride the rest (memory-bound)

    clifford_gp_kernel<<<blocks, block, 0, stream>>>(a, b, out, nrows);
}